// Round 1
// baseline (96.780 us; speedup 1.0000x reference)
//
#include <hip/hip_runtime.h>

// Problem: B=32, T=512, C=256, F=512.
// Reference softmax is over a size-1 axis -> att == 1.0 exactly.
// Therefore out[b,c,f] = sum_t x[b,t,f], broadcast over c.
// context / W / b are dead inputs. Pure bandwidth problem:
// read 33.5 MB (x) + write 16.8 MB (out).

#define BB 32
#define TT 512
#define CC 256
#define FF 512
#define F4 (FF / 4) // 128 float4 per row

// Kernel 1: partial column sums over T.
// grid = B * tsplit blocks, 128 threads (one float4 lane per f4).
// Each block streams a contiguous (trows * FF) float slab of x.
__global__ __launch_bounds__(128) void colsum_partial(const float4* __restrict__ x4,
                                                      float4* __restrict__ part4,
                                                      int tsplit, int trows) {
    const int blk = blockIdx.x;          // b * tsplit + ts
    const int j   = threadIdx.x;         // 0..127 -> f4 index
    const int b   = blk / tsplit;
    const int ts  = blk - b * tsplit;

    const float4* xp = x4 + (size_t)b * TT * F4 + (size_t)ts * trows * F4 + j;

    float4 a0 = make_float4(0.f, 0.f, 0.f, 0.f);
    float4 a1 = make_float4(0.f, 0.f, 0.f, 0.f);
    int t = 0;
    for (; t + 1 < trows; t += 2) {
        float4 v0 = xp[(size_t)t * F4];
        float4 v1 = xp[(size_t)(t + 1) * F4];
        a0.x += v0.x; a0.y += v0.y; a0.z += v0.z; a0.w += v0.w;
        a1.x += v1.x; a1.y += v1.y; a1.z += v1.z; a1.w += v1.w;
    }
    for (; t < trows; ++t) {
        float4 v0 = xp[(size_t)t * F4];
        a0.x += v0.x; a0.y += v0.y; a0.z += v0.z; a0.w += v0.w;
    }
    float4 acc = make_float4(a0.x + a1.x, a0.y + a1.y, a0.z + a1.z, a0.w + a1.w);
    part4[(size_t)blk * F4 + j] = acc;
}

// Kernel 2: finish the reduction (tsplit partials, L2-hot) once per (b, f4),
// then broadcast-store across 32 c-rows. grid = B * (C/32) = 256 blocks,
// 256 threads: tid -> (cg in {0,1}, f4 in 0..127).
__global__ __launch_bounds__(256) void bcast_out(const float4* __restrict__ part4,
                                                 float4* __restrict__ out4,
                                                 int tsplit) {
    const int CB = 32;                       // c-rows per block
    const int f4 = threadIdx.x & 127;
    const int cg = threadIdx.x >> 7;         // 0 or 1
    const int b  = blockIdx.x >> 3;          // / (C/CB) = 8
    const int cb = (blockIdx.x & 7) * CB;

    const float4* pp = part4 + (size_t)b * tsplit * F4 + f4;
    float4 acc = make_float4(0.f, 0.f, 0.f, 0.f);
    for (int ts = 0; ts < tsplit; ++ts) {
        float4 v = pp[(size_t)ts * F4];
        acc.x += v.x; acc.y += v.y; acc.z += v.z; acc.w += v.w;
    }

    float4* op = out4 + (size_t)b * CC * F4 + f4;
    for (int c = cb + cg; c < cb + CB; c += 2) {
        op[(size_t)c * F4] = acc;           // 64 lanes -> 1 KB contiguous store
    }
}

extern "C" void kernel_launch(void* const* d_in, const int* in_sizes, int n_in,
                              void* d_out, int out_size, void* d_ws, size_t ws_size,
                              hipStream_t stream) {
    const float* x = (const float*)d_in[0];   // [B,T,F] fp32
    // d_in[1] (context), d_in[2] (W), d_in[3] (b) are dead: softmax over a
    // size-1 axis is identically 1.0, so they cancel out of the output.
    float* out = (float*)d_out;               // [B,C,F] fp32

    // Pick T-split by available workspace (partials = B*tsplit*F floats).
    int tsplit = 32;                                            // 2 MB ws
    if (ws_size < (size_t)BB * tsplit * FF * sizeof(float)) tsplit = 8;   // 512 KB
    if (ws_size < (size_t)BB * tsplit * FF * sizeof(float)) tsplit = 2;   // 128 KB
    const int trows = TT / tsplit;

    colsum_partial<<<BB * tsplit, 128, 0, stream>>>(
        (const float4*)x, (float4*)d_ws, tsplit, trows);
    bcast_out<<<BB * (CC / 32), 256, 0, stream>>>(
        (const float4*)d_ws, (float4*)out, tsplit);
}